// Round 4
// baseline (1753.205 us; speedup 1.0000x reference)
//
#include <hip/hip_runtime.h>

#define B_    1024
#define T_    256
#define LOCN  40001
#define E_    100
#define H_    100
#define NC    600   // [0,400): gates (i|f|g|o) preact, [400,500): t preact, [500,600): s preact

// ---------------------------------------------------------------------------
// Kernel 1: P_loc[LOC][600] = emb_loc @ [W_ih | W_xt | W_xs] + [b | b_t | b_s]
// (round-0 proven version, PROWS=16)
// ---------------------------------------------------------------------------
constexpr int PROWS = 16;
constexpr int PPAD  = 20;   // pad 16->20 dwords: keeps 16B alignment for b128, breaks pow2 bank stride

__global__ __launch_bounds__(320) void proj_loc_kernel(
    const float* __restrict__ emb_loc,
    const float* __restrict__ W_ih,   // [100][400]
    const float* __restrict__ W_xt,   // [100][100]
    const float* __restrict__ W_xs,   // [100][100]
    const float* __restrict__ b,      // [400]
    const float* __restrict__ b_t,    // [100]
    const float* __restrict__ b_s,    // [100]
    float* __restrict__ P)            // [LOC][600]
{
    __shared__ __attribute__((aligned(16))) float aT[E_][PPAD];  // transposed tile
    const int tid  = threadIdx.x;
    const int row0 = blockIdx.x * PROWS;

    for (int i = tid; i < PROWS * E_; i += 320) {
        int r = i / E_, k = i - r * E_;
        int rr = row0 + r;
        float v = 0.f;
        if (rr < LOCN) v = emb_loc[rr * E_ + k];
        aT[k][r] = v;
    }
    __syncthreads();
    if (tid >= 300) return;

    for (int cc = 0; cc < 2; ++cc) {
        const int c = tid + cc * 300;
        const float* wp; int stride; float bias;
        if (c < 400)      { wp = W_ih + c;         stride = 400; bias = b[c]; }
        else if (c < 500) { wp = W_xt + (c - 400); stride = 100; bias = b_t[c - 400]; }
        else              { wp = W_xs + (c - 500); stride = 100; bias = b_s[c - 500]; }

        float acc[PROWS];
        #pragma unroll
        for (int r = 0; r < PROWS; ++r) acc[r] = bias;

        for (int k = 0; k < E_; ++k) {
            float w = wp[(size_t)k * stride];
            #pragma unroll
            for (int r = 0; r < PROWS; ++r) acc[r] += aT[k][r] * w;
        }
        #pragma unroll
        for (int r = 0; r < PROWS; ++r) {
            int rr = row0 + r;
            if (rr < LOCN) P[(size_t)rr * NC + c] = acc[r];
        }
    }
}

// ---------------------------------------------------------------------------
// Kernel 2: P_t[92][100] = emb_t @ W_tt ; P_s[92][100] = emb_s @ W_ss
// ---------------------------------------------------------------------------
__global__ void proj_ts_kernel(
    const float* __restrict__ emb_t, const float* __restrict__ emb_s,
    const float* __restrict__ W_tt,  const float* __restrict__ W_ss,
    float* __restrict__ P_t, float* __restrict__ P_s)
{
    int idx = blockIdx.x * 256 + threadIdx.x;
    if (idx >= 2 * 92 * H_) return;
    int which = idx / (92 * H_);
    int rem   = idx - which * (92 * H_);
    int r = rem / H_, c = rem - r * H_;
    const float* e = which ? emb_s : emb_t;
    const float* W = which ? W_ss : W_tt;
    float acc = 0.f;
    #pragma unroll
    for (int k = 0; k < 12; ++k) acc += e[r * 12 + k] * W[k * H_ + c];
    (which ? P_s : P_t)[rem] = acc;
}

// ---------------------------------------------------------------------------
// Kernel 3: recurrence. 256 blocks x 704 threads, RB=4 rows/block, 1 blk/CU.
// W_hh lives in LDS (Wt[400 cols][100 k], 156.25 KB) -- staged ONCE, read
// every step via conflict-free ds_read_b128 (within a wave n&7 is uniform
// because n = gi*100+q and 100 % 8 == 4). This removes round-0's hidden
// limiter: 160 KB/CU/step of W_hh re-streaming from L2 (~2850 cyc/step of
// per-CU L2 BW, invisible to FETCH_SIZE).
//   tid<400 : gate col n=(tid&3)*100+(tid>>2); i/f/g/o of one h-index in 4
//             adjacent lanes; preacts in regs; epilogue via 3 shfl_xor
//             (gates_lds eliminated -> LDS budget fits).
//   tid in [448,648): ts channel ch=tid-448; hx=ch>>1; even lane = t-gate,
//             odd = s-gate; pair product via shfl_xor(1) -> tsg_lds.
// Two __syncthreads per step; h and tsg single-buffered.
// ---------------------------------------------------------------------------
constexpr int RB = 4;
constexpr int NT = 704;

__global__ __launch_bounds__(NT) void lstm_rec_kernel(
    const int* __restrict__ traj,
    const int* __restrict__ traj_len_p,
    const int* __restrict__ tu,      const int* __restrict__ tl,
    const int* __restrict__ tu_slot, const int* __restrict__ tl_slot,
    const int* __restrict__ su,      const int* __restrict__ sl,
    const int* __restrict__ su_slot, const int* __restrict__ sl_slot,
    const float* __restrict__ P,     // [LOC][600]
    const float* __restrict__ P_t,   // [92][100]
    const float* __restrict__ P_s,   // [92][100]
    const float* __restrict__ W_hh,  // [100][400]
    float* __restrict__ out)         // [B][100]
{
    __shared__ __attribute__((aligned(16))) float Wt[400 * H_];   // [n][k] 160,000 B
    __shared__ __attribute__((aligned(16))) float h_lds[RB][H_];  //   1,600 B
    __shared__ __attribute__((aligned(16))) float tsg_lds[RB][H_];//   1,600 B

    const int tid = threadIdx.x;
    const int b0  = blockIdx.x * RB;
    int steps = traj_len_p[0] + 1;
    if (steps > T_) steps = T_;
    steps = __builtin_amdgcn_readfirstlane(steps);

    // ---- stage Wt[n][k] = W_hh[k][n] (one-time; coalesced global reads) ----
    for (int i = tid; i < E_ * 400; i += NT) {
        const int k  = i / 400;
        const int nn = i - k * 400;
        Wt[nn * H_ + k] = W_hh[i];
    }
    if (tid < RB * H_) ((float*)h_lds)[tid] = 0.f;

    // ---- role constants ----
    const bool isGate = tid < 400;
    const int  gi = tid & 3;            // 0=i 1=f 2=g 3=o
    const int  q  = tid >> 2;           // h-index
    const int  n  = gi * 100 + q;       // preact / W column

    const int  ch   = tid - 448;        // valid when isTS
    const bool isTS = (tid >= 448) && (tid < 648);
    const int  hx   = ch >> 1;
    const bool lane_t = !(ch & 1);      // even lane = t-gate, odd = s-gate
    const int* up_a = lane_t ? tu_slot : su_slot;
    const int* lo_a = lane_t ? tl_slot : sl_slot;
    const int* ui_a = lane_t ? tu : su;
    const int* li_a = lane_t ? tl : sl;
    const float* Pq = lane_t ? P_t : P_s;
    const int  gcol = (lane_t ? 400 : 500) + hx;

    // per-row traj bases + loc registers (prefetched one step ahead)
    int tb[RB], lcur[RB], lnxt[RB];
    #pragma unroll
    for (int r = 0; r < RB; ++r) {
        tb[r]   = (b0 + r) * T_;
        lcur[r] = traj[tb[r]];          // broadcast load (same addr per wave)
    }

    float c_reg[RB] = {0.f, 0.f, 0.f, 0.f};
    __syncthreads();                    // Wt + h ready

    for (int t = 0; t < steps; ++t) {
        const int tn = (t + 1 < steps) ? t + 1 : t;   // clamped next index
        float pre[RB];

        if (tid < 648) {                // prefetch next step's locs (broadcast)
            #pragma unroll
            for (int r = 0; r < RB; ++r) lnxt[r] = traj[tb[r] + tn];
        }

        if (isGate) {                   // ---- gather + h @ W_hh (from LDS) ----
            float gacc[RB];
            #pragma unroll
            for (int r = 0; r < RB; ++r)
                gacc[r] = P[(size_t)lcur[r] * NC + n];

            float acc[RB] = {0.f, 0.f, 0.f, 0.f};
            const float* wp = &Wt[n * H_];
            #pragma unroll
            for (int k4 = 0; k4 < H_ / 4; ++k4) {
                const float4 wv = *(const float4*)(&wp[k4 * 4]);
                #pragma unroll
                for (int r = 0; r < RB; ++r) {
                    const float4 hv = *(const float4*)(&h_lds[r][k4 * 4]);
                    acc[r] += hv.x * wv.x;
                    acc[r] += hv.y * wv.y;
                    acc[r] += hv.z * wv.z;
                    acc[r] += hv.w * wv.w;
                }
            }
            #pragma unroll
            for (int r = 0; r < RB; ++r) pre[r] = acc[r] + gacc[r];
        }

        if (isTS) {                     // ---- t/s gates -> product in tsg_lds ----
            #pragma unroll
            for (int r = 0; r < RB; ++r) {
                const int off = tb[r] + t;
                const float gp  = P[(size_t)lcur[r] * NC + gcol];
                const float up  = (float)up_a[off];
                const float low = (float)lo_a[off];
                const int   ui  = ui_a[off], li = li_a[off];
                const float iv  = (up * Pq[li * H_ + hx] + low * Pq[ui * H_ + hx])
                                  / fmaxf(up + low, 1.f);
                const float v   = 1.f / (1.f + expf(-(gp + iv)));
                const float pv  = __shfl_xor(v, 1);
                if (lane_t) tsg_lds[r][hx] = v * pv;
            }
        }
        __syncthreads();                // tsg ready; all h reads done

        if (isGate) {                   // ---- act + shuffle epilogue ----
            #pragma unroll
            for (int r = 0; r < RB; ++r) {
                const float v  = pre[r];
                const bool isg = (gi == 2);                 // g-gate -> tanh
                const float x  = isg ? 2.f * v : v;
                const float s  = 1.f / (1.f + expf(-x));
                const float a  = isg ? 2.f * s - 1.f : s;
                const float x1 = __shfl_xor(a, 1);          // lane0: f
                const float x2 = __shfl_xor(a, 2);          // lane0: g
                const float x3 = __shfl_xor(x1, 2);         // lane0: o
                if (gi == 0) {
                    const float tsv = tsg_lds[r][q];
                    c_reg[r] = x1 * c_reg[r] + a * tsv * x2;
                    h_lds[r][q] = x3 * tanhf(c_reg[r]);
                }
            }
        }
        #pragma unroll
        for (int r = 0; r < RB; ++r) lcur[r] = lnxt[r];
        __syncthreads();                // h ready for next step
    }

    if (tid < 400) {
        const int r  = tid / 100;
        const int qq = tid - r * 100;
        out[(b0 + r) * H_ + qq] = h_lds[r][qq];
    }
}

// ---------------------------------------------------------------------------
extern "C" void kernel_launch(void* const* d_in, const int* in_sizes, int n_in,
                              void* d_out, int out_size, void* d_ws, size_t ws_size,
                              hipStream_t stream) {
    const int*   traj     = (const int*)  d_in[0];
    // d_in[1] = lennew (unused by the reference)
    const int*   traj_len = (const int*)  d_in[2];
    const int*   tu       = (const int*)  d_in[3];
    const int*   tl       = (const int*)  d_in[4];
    const int*   tu_slot  = (const int*)  d_in[5];
    const int*   tl_slot  = (const int*)  d_in[6];
    const int*   su       = (const int*)  d_in[7];
    const int*   sl       = (const int*)  d_in[8];
    const int*   su_slot  = (const int*)  d_in[9];
    const int*   sl_slot  = (const int*)  d_in[10];
    const float* emb_loc  = (const float*)d_in[11];
    const float* emb_t    = (const float*)d_in[12];
    const float* emb_s    = (const float*)d_in[13];
    const float* W_ih     = (const float*)d_in[14];
    const float* W_hh     = (const float*)d_in[15];
    const float* b        = (const float*)d_in[16];
    const float* W_xt     = (const float*)d_in[17];
    const float* W_tt     = (const float*)d_in[18];
    const float* b_t      = (const float*)d_in[19];
    const float* W_xs     = (const float*)d_in[20];
    const float* W_ss     = (const float*)d_in[21];
    const float* b_s      = (const float*)d_in[22];

    float* P   = (float*)d_ws;              // 40001*600 = 24,000,600 floats (96.0 MB)
    float* P_t = P + (size_t)LOCN * NC;     // 9200 floats
    float* P_s = P_t + 92 * H_;             // 9200 floats

    proj_loc_kernel<<<(LOCN + PROWS - 1) / PROWS, 320, 0, stream>>>(
        emb_loc, W_ih, W_xt, W_xs, b, b_t, b_s, P);
    proj_ts_kernel<<<(2 * 92 * H_ + 255) / 256, 256, 0, stream>>>(
        emb_t, emb_s, W_tt, W_ss, P_t, P_s);
    lstm_rec_kernel<<<B_ / RB, NT, 0, stream>>>(
        traj, traj_len, tu, tl, tu_slot, tl_slot, su, sl, su_slot, sl_slot,
        P, P_t, P_s, W_hh, (float*)d_out);
}

// Round 5
// 897.085 us; speedup vs baseline: 1.9543x; 1.9543x over previous
//
#include <hip/hip_runtime.h>

#define B_    1024
#define T_    256
#define LOCN  40001
#define E_    100
#define H_    100
#define NC    600   // [0,400): gates (i|f|g|o) preact, [400,500): t preact, [500,600): s preact

// ---------------------------------------------------------------------------
// Kernel 1: P_loc[LOC][600] = emb_loc @ [W_ih | W_xt | W_xs] + [b | b_t | b_s]
// (round-0 proven version, PROWS=16)
// ---------------------------------------------------------------------------
constexpr int PROWS = 16;
constexpr int PPAD  = 20;   // pad 16->20 dwords: keeps 16B alignment for b128, breaks pow2 bank stride

__global__ __launch_bounds__(320) void proj_loc_kernel(
    const float* __restrict__ emb_loc,
    const float* __restrict__ W_ih,   // [100][400]
    const float* __restrict__ W_xt,   // [100][100]
    const float* __restrict__ W_xs,   // [100][100]
    const float* __restrict__ b,      // [400]
    const float* __restrict__ b_t,    // [100]
    const float* __restrict__ b_s,    // [100]
    float* __restrict__ P)            // [LOC][600]
{
    __shared__ __attribute__((aligned(16))) float aT[E_][PPAD];  // transposed tile
    const int tid  = threadIdx.x;
    const int row0 = blockIdx.x * PROWS;

    for (int i = tid; i < PROWS * E_; i += 320) {
        int r = i / E_, k = i - r * E_;
        int rr = row0 + r;
        float v = 0.f;
        if (rr < LOCN) v = emb_loc[rr * E_ + k];
        aT[k][r] = v;
    }
    __syncthreads();
    if (tid >= 300) return;

    for (int cc = 0; cc < 2; ++cc) {
        const int c = tid + cc * 300;
        const float* wp; int stride; float bias;
        if (c < 400)      { wp = W_ih + c;         stride = 400; bias = b[c]; }
        else if (c < 500) { wp = W_xt + (c - 400); stride = 100; bias = b_t[c - 400]; }
        else              { wp = W_xs + (c - 500); stride = 100; bias = b_s[c - 500]; }

        float acc[PROWS];
        #pragma unroll
        for (int r = 0; r < PROWS; ++r) acc[r] = bias;

        for (int k = 0; k < E_; ++k) {
            float w = wp[(size_t)k * stride];
            #pragma unroll
            for (int r = 0; r < PROWS; ++r) acc[r] += aT[k][r] * w;
        }
        #pragma unroll
        for (int r = 0; r < PROWS; ++r) {
            int rr = row0 + r;
            if (rr < LOCN) P[(size_t)rr * NC + c] = acc[r];
        }
    }
}

// ---------------------------------------------------------------------------
// Kernel 2: P_t[92][100] = emb_t @ W_tt ; P_s[92][100] = emb_s @ W_ss
// ---------------------------------------------------------------------------
__global__ void proj_ts_kernel(
    const float* __restrict__ emb_t, const float* __restrict__ emb_s,
    const float* __restrict__ W_tt,  const float* __restrict__ W_ss,
    float* __restrict__ P_t, float* __restrict__ P_s)
{
    int idx = blockIdx.x * 256 + threadIdx.x;
    if (idx >= 2 * 92 * H_) return;
    int which = idx / (92 * H_);
    int rem   = idx - which * (92 * H_);
    int r = rem / H_, c = rem - r * H_;
    const float* e = which ? emb_s : emb_t;
    const float* W = which ? W_ss : W_tt;
    float acc = 0.f;
    #pragma unroll
    for (int k = 0; k < 12; ++k) acc += e[r * 12 + k] * W[k * H_ + c];
    (which ? P_s : P_t)[rem] = acc;
}

// ---------------------------------------------------------------------------
// Kernel 3: recurrence. 256 blocks x 1024 threads, RB=4 rows/block, 1 blk/CU.
// Diagnosis history: round-0/3 kept w[100] in AGPRs (84 VGPR + ~100 AGPR =
// register file exactly full at 2.75 waves/SIMD); every FMA paid accvgpr
// traffic -> ~2x VALU issue. Round-4 (W in LDS) choked the LDS pipe.
// Fix: k-split w across lane PAIRS so each thread holds only w[52] -> true
// VGPRs under the 128 cap (launch_bounds(1024,4)), 16 waves/CU.
//   tid<800  : gate. lane pair (2n,2n+1) owns col n; half=tid&1 selects
//              k in [0,52) / [52,104) (h_lds padded to 104, pad=0).
//              acc pair-combined via shfl_xor(1); even lane activates rows
//              0,1, odd lane rows 2,3 -> gates_lds[r][n].
//   tid [832,932): ts. hx=tid-832; computes BOTH t and s gates for 4 rows,
//              writes product tg*sg -> tsg_lds.
//   tid [960,964): loc double-buffer prefetch.
// Two __syncthreads per step (round-0 proven skeleton).
// ---------------------------------------------------------------------------
constexpr int RB = 4;
constexpr int NT = 1024;
constexpr int HP = 104;   // padded h length (2 x 52)

__global__ __launch_bounds__(NT, 4) void lstm_rec_kernel(
    const int* __restrict__ traj,
    const int* __restrict__ traj_len_p,
    const int* __restrict__ tu,      const int* __restrict__ tl,
    const int* __restrict__ tu_slot, const int* __restrict__ tl_slot,
    const int* __restrict__ su,      const int* __restrict__ sl,
    const int* __restrict__ su_slot, const int* __restrict__ sl_slot,
    const float* __restrict__ P,     // [LOC][600]
    const float* __restrict__ P_t,   // [92][100]
    const float* __restrict__ P_s,   // [92][100]
    const float* __restrict__ W_hh,  // [100][400]
    float* __restrict__ out)         // [B][100]
{
    __shared__ __attribute__((aligned(16))) float h_lds[RB][HP];
    __shared__ float gates_lds[RB][400];
    __shared__ float tsg_lds[RB][H_];
    __shared__ int   loc_lds[2][RB];

    const int tid = threadIdx.x;
    const int b0  = blockIdx.x * RB;
    int steps = traj_len_p[0] + 1;
    if (steps > T_) steps = T_;
    steps = __builtin_amdgcn_readfirstlane(steps);

    const bool isGate = tid < 800;
    const int  half = tid & 1;        // 0: k in [0,52), 1: k in [52,104)
    const int  n    = tid >> 1;       // gate column (valid when isGate)
    const int  kb   = half * 52;

    // zero h (incl. pad [100,104) which must stay 0 forever)
    for (int i = tid; i < RB * HP; i += NT) ((float*)h_lds)[i] = 0.f;
    if (tid < RB) loc_lds[0][tid] = traj[(b0 + tid) * T_];

    // w slice -> true VGPRs (pin forces VGPR class, defeats AGPR offload)
    float w[52];
    if (isGate) {
        #pragma unroll
        for (int j = 0; j < 52; ++j) {
            const int k = kb + j;
            w[j] = (k < 100) ? W_hh[k * 400 + n] : 0.f;
        }
        #pragma unroll
        for (int j = 0; j < 52; ++j) asm volatile("" : "+v"(w[j]));
    }

    const int er = tid / 100;        // epilogue row   (valid for tid<400)
    const int eh = tid - er * 100;   // epilogue h-idx
    float c_reg = 0.f, hval = 0.f;
    __syncthreads();

    for (int t = 0; t < steps; ++t) {
        const int buf = t & 1;

        if (tid >= 960 && tid < 964) {          // prefetch next step's locations
            const int r = tid - 960;
            if (t + 1 < steps) loc_lds[buf ^ 1][r] = traj[(b0 + r) * T_ + t + 1];
        }

        if (isGate) {                           // ---- gather + h @ W_hh ----
            float gacc[RB] = {0.f, 0.f, 0.f, 0.f};
            if (half == 0) {
                #pragma unroll
                for (int r = 0; r < RB; ++r)
                    gacc[r] = P[(size_t)loc_lds[buf][r] * NC + n];
            }
            float acc[RB];
            #pragma unroll
            for (int r = 0; r < RB; ++r) acc[r] = gacc[r];
            #pragma unroll
            for (int j4 = 0; j4 < 13; ++j4) {
                #pragma unroll
                for (int r = 0; r < RB; ++r) {
                    const float4 hv = *(const float4*)(&h_lds[r][kb + j4 * 4]);
                    acc[r] += hv.x * w[j4 * 4 + 0];
                    acc[r] += hv.y * w[j4 * 4 + 1];
                    acc[r] += hv.z * w[j4 * 4 + 2];
                    acc[r] += hv.w * w[j4 * 4 + 3];
                }
            }
            // pair combine: both lanes get the full k-sum
            const float v0 = acc[0] + __shfl_xor(acc[0], 1);
            const float v1 = acc[1] + __shfl_xor(acc[1], 1);
            const float v2 = acc[2] + __shfl_xor(acc[2], 1);
            const float v3 = acc[3] + __shfl_xor(acc[3], 1);
            // each lane activates 2 rows: even -> rows 0,1 ; odd -> rows 2,3
            const bool  isg = (n >= 200 && n < 300);   // g-gate -> tanh via 2*sig(2x)-1
            const float va  = half ? v2 : v0;
            const float vb  = half ? v3 : v1;
            const float xa  = isg ? 2.f * va : va;
            const float xb  = isg ? 2.f * vb : vb;
            const float sa  = 1.f / (1.f + expf(-xa));
            const float sb  = 1.f / (1.f + expf(-xb));
            const float aa  = isg ? (2.f * sa - 1.f) : sa;
            const float ab  = isg ? (2.f * sb - 1.f) : sb;
            const int   rA  = half * 2;
            gates_lds[rA][n]     = aa;
            gates_lds[rA + 1][n] = ab;
        }

        if (tid >= 832 && tid < 932) {          // ---- t AND s gates -> product ----
            const int hx = tid - 832;
            #pragma unroll
            for (int r = 0; r < RB; ++r) {
                const int off = (b0 + r) * T_ + t;
                const int loc = loc_lds[buf][r];
                // t gate
                const float gpt = P[(size_t)loc * NC + 400 + hx];
                const float upt = (float)tu_slot[off];
                const float lot = (float)tl_slot[off];
                const int   uit = tu[off], lit = tl[off];
                const float ivt = (upt * P_t[lit * H_ + hx] + lot * P_t[uit * H_ + hx])
                                  / fmaxf(upt + lot, 1.f);
                const float tv  = 1.f / (1.f + expf(-(gpt + ivt)));
                // s gate
                const float gps = P[(size_t)loc * NC + 500 + hx];
                const float ups = (float)su_slot[off];
                const float los = (float)sl_slot[off];
                const int   uis = su[off], lis = sl[off];
                const float ivs = (ups * P_s[lis * H_ + hx] + los * P_s[uis * H_ + hx])
                                  / fmaxf(ups + los, 1.f);
                const float sv  = 1.f / (1.f + expf(-(gps + ivs)));
                tsg_lds[r][hx] = tv * sv;
            }
        }
        __syncthreads();

        if (tid < 400) {                        // ---- epilogue: c,h update ----
            const float i_g = gates_lds[er][eh];
            const float f_g = gates_lds[er][100 + eh];
            const float g_g = gates_lds[er][200 + eh];
            const float o_g = gates_lds[er][300 + eh];
            const float tsg = tsg_lds[er][eh];
            c_reg = f_g * c_reg + i_g * tsg * g_g;
            hval  = o_g * tanhf(c_reg);
            h_lds[er][eh] = hval;
        }
        __syncthreads();
    }

    if (tid < 400) out[b0 * H_ + tid] = hval;
}

// ---------------------------------------------------------------------------
extern "C" void kernel_launch(void* const* d_in, const int* in_sizes, int n_in,
                              void* d_out, int out_size, void* d_ws, size_t ws_size,
                              hipStream_t stream) {
    const int*   traj     = (const int*)  d_in[0];
    // d_in[1] = lennew (unused by the reference)
    const int*   traj_len = (const int*)  d_in[2];
    const int*   tu       = (const int*)  d_in[3];
    const int*   tl       = (const int*)  d_in[4];
    const int*   tu_slot  = (const int*)  d_in[5];
    const int*   tl_slot  = (const int*)  d_in[6];
    const int*   su       = (const int*)  d_in[7];
    const int*   sl       = (const int*)  d_in[8];
    const int*   su_slot  = (const int*)  d_in[9];
    const int*   sl_slot  = (const int*)  d_in[10];
    const float* emb_loc  = (const float*)d_in[11];
    const float* emb_t    = (const float*)d_in[12];
    const float* emb_s    = (const float*)d_in[13];
    const float* W_ih     = (const float*)d_in[14];
    const float* W_hh     = (const float*)d_in[15];
    const float* b        = (const float*)d_in[16];
    const float* W_xt     = (const float*)d_in[17];
    const float* W_tt     = (const float*)d_in[18];
    const float* b_t      = (const float*)d_in[19];
    const float* W_xs     = (const float*)d_in[20];
    const float* W_ss     = (const float*)d_in[21];
    const float* b_s      = (const float*)d_in[22];

    float* P   = (float*)d_ws;              // 40001*600 = 24,000,600 floats (96.0 MB)
    float* P_t = P + (size_t)LOCN * NC;     // 9200 floats
    float* P_s = P_t + 92 * H_;             // 9200 floats

    proj_loc_kernel<<<(LOCN + PROWS - 1) / PROWS, 320, 0, stream>>>(
        emb_loc, W_ih, W_xt, W_xs, b, b_t, b_s, P);
    proj_ts_kernel<<<(2 * 92 * H_ + 255) / 256, 256, 0, stream>>>(
        emb_t, emb_s, W_tt, W_ss, P_t, P_s);
    lstm_rec_kernel<<<B_ / RB, NT, 0, stream>>>(
        traj, traj_len, tu, tl, tu_slot, tl_slot, su, sl, su_slot, sl_slot,
        P, P_t, P_s, W_hh, (float*)d_out);
}

// Round 6
// 886.432 us; speedup vs baseline: 1.9778x; 1.0120x over previous
//
#include <hip/hip_runtime.h>

#define B_    1024
#define T_    256
#define LOCN  40001
#define E_    100
#define H_    100
#define NC    600   // [0,400): gates (i|f|g|o) preact, [400,500): t preact, [500,600): s preact

// ---------------------------------------------------------------------------
// Kernel 1: P_loc[LOC][600] = emb_loc @ [W_ih | W_xt | W_xs] + [b | b_t | b_s]
// (round-0 proven version, PROWS=16)
// ---------------------------------------------------------------------------
constexpr int PROWS = 16;
constexpr int PPAD  = 20;   // pad 16->20 dwords: keeps 16B alignment for b128, breaks pow2 bank stride

__global__ __launch_bounds__(320) void proj_loc_kernel(
    const float* __restrict__ emb_loc,
    const float* __restrict__ W_ih,   // [100][400]
    const float* __restrict__ W_xt,   // [100][100]
    const float* __restrict__ W_xs,   // [100][100]
    const float* __restrict__ b,      // [400]
    const float* __restrict__ b_t,    // [100]
    const float* __restrict__ b_s,    // [100]
    float* __restrict__ P)            // [LOC][600]
{
    __shared__ __attribute__((aligned(16))) float aT[E_][PPAD];  // transposed tile
    const int tid  = threadIdx.x;
    const int row0 = blockIdx.x * PROWS;

    for (int i = tid; i < PROWS * E_; i += 320) {
        int r = i / E_, k = i - r * E_;
        int rr = row0 + r;
        float v = 0.f;
        if (rr < LOCN) v = emb_loc[rr * E_ + k];
        aT[k][r] = v;
    }
    __syncthreads();
    if (tid >= 300) return;

    for (int cc = 0; cc < 2; ++cc) {
        const int c = tid + cc * 300;
        const float* wp; int stride; float bias;
        if (c < 400)      { wp = W_ih + c;         stride = 400; bias = b[c]; }
        else if (c < 500) { wp = W_xt + (c - 400); stride = 100; bias = b_t[c - 400]; }
        else              { wp = W_xs + (c - 500); stride = 100; bias = b_s[c - 500]; }

        float acc[PROWS];
        #pragma unroll
        for (int r = 0; r < PROWS; ++r) acc[r] = bias;

        for (int k = 0; k < E_; ++k) {
            float w = wp[(size_t)k * stride];
            #pragma unroll
            for (int r = 0; r < PROWS; ++r) acc[r] += aT[k][r] * w;
        }
        #pragma unroll
        for (int r = 0; r < PROWS; ++r) {
            int rr = row0 + r;
            if (rr < LOCN) P[(size_t)rr * NC + c] = acc[r];
        }
    }
}

// ---------------------------------------------------------------------------
// Kernel 2: P_t[92][100] = emb_t @ W_tt ; P_s[92][100] = emb_s @ W_ss
// ---------------------------------------------------------------------------
__global__ void proj_ts_kernel(
    const float* __restrict__ emb_t, const float* __restrict__ emb_s,
    const float* __restrict__ W_tt,  const float* __restrict__ W_ss,
    float* __restrict__ P_t, float* __restrict__ P_s)
{
    int idx = blockIdx.x * 256 + threadIdx.x;
    if (idx >= 2 * 92 * H_) return;
    int which = idx / (92 * H_);
    int rem   = idx - which * (92 * H_);
    int r = rem / H_, c = rem - r * H_;
    const float* e = which ? emb_s : emb_t;
    const float* W = which ? W_ss : W_tt;
    float acc = 0.f;
    #pragma unroll
    for (int k = 0; k < 12; ++k) acc += e[r * 12 + k] * W[k * H_ + c];
    (which ? P_s : P_t)[rem] = acc;
}

// ---------------------------------------------------------------------------
// Kernel 3: recurrence. 256 blocks x 960 threads, RB=4 rows/block, 1 blk/CU.
// DIAGNOSIS (rounds 0-5): step time tracks LDS wave-instruction count, not
// VALU FMA count (broadcast ds_read_b128 still costs ~8-12 cyc: LDS ships
// 16B x 64 lanes = 1KB/inst at 128B/clk). Rounds 0/5 issued ~625-650
// broadcast h-reads/CU/step (1 column per thread -> 1 read per 4 FMAs).
// FIX: cc=2 columns/thread. Thread (p,kq) = tid>>2, tid&3 owns cols
// {2p,2p+1}, k-quarter kq*28..+28 (H padded 100->112 with zeros). Each
// h float4 read feeds 8 FMAs -> gate LDS reads/CU/step: 625 -> 350.
// k-quarter partials reduced via shfl_xor(1/2) butterfly in aligned 4-lane
// groups (quad-perm DPP = VALU pipe, not LDS). Each lane then activates 2
// (row,col) outputs: col = 2p+(kq>>1), rows {(kq&1)*2, +1}.
//   tid<800       : gate threads (above).
//   tid [832,932) : ts threads, product tg*sg (round-5 verified code).
//   tid [944,948) : loc double-buffer prefetch.
// h-read bank check: 4 distinct addrs/wave at kq*112B -> disjoint bank
// quads, 16-lane broadcast each = conflict-free.
// ---------------------------------------------------------------------------
constexpr int RB = 4;
constexpr int NT = 960;
constexpr int HP = 112;   // padded h length (4 x 28)

__global__ __launch_bounds__(NT, 4) void lstm_rec_kernel(
    const int* __restrict__ traj,
    const int* __restrict__ traj_len_p,
    const int* __restrict__ tu,      const int* __restrict__ tl,
    const int* __restrict__ tu_slot, const int* __restrict__ tl_slot,
    const int* __restrict__ su,      const int* __restrict__ sl,
    const int* __restrict__ su_slot, const int* __restrict__ sl_slot,
    const float* __restrict__ P,     // [LOC][600]
    const float* __restrict__ P_t,   // [92][100]
    const float* __restrict__ P_s,   // [92][100]
    const float* __restrict__ W_hh,  // [100][400]
    float* __restrict__ out)         // [B][100]
{
    __shared__ __attribute__((aligned(16))) float h_lds[RB][HP];
    __shared__ float gates_lds[RB][400];
    __shared__ float tsg_lds[RB][H_];
    __shared__ int   loc_lds[2][RB];

    const int tid = threadIdx.x;
    const int b0  = blockIdx.x * RB;
    int steps = traj_len_p[0] + 1;
    if (steps > T_) steps = T_;
    steps = __builtin_amdgcn_readfirstlane(steps);

    const bool isGate = tid < 800;
    const int  p   = tid >> 2;        // col-pair index 0..199 (valid when isGate)
    const int  kq  = tid & 3;         // k-quarter
    const int  kb  = kq * 28;
    const int  c0  = 2 * p;           // first owned column
    const int  csel  = kq >> 1;       // which col of the pair this lane activates
    const int  rbase = (kq & 1) * 2;  // which row pair this lane activates
    const int  acol  = c0 + csel;     // activated column

    // zero h (incl. pad [100,112) which must stay 0 forever)
    for (int i = tid; i < RB * HP; i += NT) ((float*)h_lds)[i] = 0.f;
    if (tid < RB) loc_lds[0][tid] = traj[(b0 + tid) * T_];

    // w slices -> registers (28 per owned column; zero-padded past k=99)
    float w0[28], w1[28];
    if (isGate) {
        #pragma unroll
        for (int j = 0; j < 28; ++j) {
            const int k = kb + j;
            w0[j] = (k < 100) ? W_hh[k * 400 + c0]     : 0.f;
            w1[j] = (k < 100) ? W_hh[k * 400 + c0 + 1] : 0.f;
        }
        #pragma unroll
        for (int j = 0; j < 28; ++j) {
            asm volatile("" : "+v"(w0[j]));
            asm volatile("" : "+v"(w1[j]));
        }
    }

    const int er = tid / 100;        // epilogue row   (valid for tid<400)
    const int eh = tid - er * 100;   // epilogue h-idx
    float c_reg = 0.f, hval = 0.f;
    __syncthreads();

    for (int t = 0; t < steps; ++t) {
        const int buf = t & 1;

        if (tid >= 944 && tid < 948) {          // prefetch next step's locations
            const int r = tid - 944;
            if (t + 1 < steps) loc_lds[buf ^ 1][r] = traj[(b0 + r) * T_ + t + 1];
        }

        if (isGate) {                           // ---- h @ W_hh, cc=2 ----
            // gather preacts for this lane's 2 outputs (scattered, issued early)
            const int locA = loc_lds[buf][rbase];
            const int locB = loc_lds[buf][rbase + 1];
            const float gpA = P[(size_t)locA * NC + acol];
            const float gpB = P[(size_t)locB * NC + acol];

            float acc[RB][2];
            #pragma unroll
            for (int r = 0; r < RB; ++r) { acc[r][0] = 0.f; acc[r][1] = 0.f; }
            #pragma unroll
            for (int j4 = 0; j4 < 7; ++j4) {
                #pragma unroll
                for (int r = 0; r < RB; ++r) {
                    const float4 hv = *(const float4*)(&h_lds[r][kb + j4 * 4]);
                    acc[r][0] += hv.x * w0[j4 * 4 + 0];
                    acc[r][0] += hv.y * w0[j4 * 4 + 1];
                    acc[r][0] += hv.z * w0[j4 * 4 + 2];
                    acc[r][0] += hv.w * w0[j4 * 4 + 3];
                    acc[r][1] += hv.x * w1[j4 * 4 + 0];
                    acc[r][1] += hv.y * w1[j4 * 4 + 1];
                    acc[r][1] += hv.z * w1[j4 * 4 + 2];
                    acc[r][1] += hv.w * w1[j4 * 4 + 3];
                }
            }
            // butterfly over the 4 k-quarters (aligned 4-lane groups, DPP)
            float red[RB][2];
            #pragma unroll
            for (int r = 0; r < RB; ++r) {
                #pragma unroll
                for (int c = 0; c < 2; ++c) {
                    float v = acc[r][c];
                    v += __shfl_xor(v, 1);
                    v += __shfl_xor(v, 2);
                    red[r][c] = v;
                }
            }
            // this lane's 2 outputs: rows rbase,rbase+1 of column acol
            const float sumA = rbase ? (csel ? red[2][1] : red[2][0])
                                     : (csel ? red[0][1] : red[0][0]);
            const float sumB = rbase ? (csel ? red[3][1] : red[3][0])
                                     : (csel ? red[1][1] : red[1][0]);
            const bool  isg = (acol >= 200 && acol < 300);  // g-gate -> tanh
            const float vA  = sumA + gpA;
            const float vB  = sumB + gpB;
            const float xA  = isg ? 2.f * vA : vA;
            const float xB  = isg ? 2.f * vB : vB;
            const float sA  = 1.f / (1.f + expf(-xA));
            const float sB  = 1.f / (1.f + expf(-xB));
            gates_lds[rbase][acol]     = isg ? (2.f * sA - 1.f) : sA;
            gates_lds[rbase + 1][acol] = isg ? (2.f * sB - 1.f) : sB;
        }

        if (tid >= 832 && tid < 932) {          // ---- t AND s gates -> product ----
            const int hx = tid - 832;
            #pragma unroll
            for (int r = 0; r < RB; ++r) {
                const int off = (b0 + r) * T_ + t;
                const int loc = loc_lds[buf][r];
                // t gate
                const float gpt = P[(size_t)loc * NC + 400 + hx];
                const float upt = (float)tu_slot[off];
                const float lot = (float)tl_slot[off];
                const int   uit = tu[off], lit = tl[off];
                const float ivt = (upt * P_t[lit * H_ + hx] + lot * P_t[uit * H_ + hx])
                                  / fmaxf(upt + lot, 1.f);
                const float tv  = 1.f / (1.f + expf(-(gpt + ivt)));
                // s gate
                const float gps = P[(size_t)loc * NC + 500 + hx];
                const float ups = (float)su_slot[off];
                const float los = (float)sl_slot[off];
                const int   uis = su[off], lis = sl[off];
                const float ivs = (ups * P_s[lis * H_ + hx] + los * P_s[uis * H_ + hx])
                                  / fmaxf(ups + los, 1.f);
                const float sv  = 1.f / (1.f + expf(-(gps + ivs)));
                tsg_lds[r][hx] = tv * sv;
            }
        }
        __syncthreads();

        if (tid < 400) {                        // ---- epilogue: c,h update ----
            const float i_g = gates_lds[er][eh];
            const float f_g = gates_lds[er][100 + eh];
            const float g_g = gates_lds[er][200 + eh];
            const float o_g = gates_lds[er][300 + eh];
            const float tsg = tsg_lds[er][eh];
            c_reg = f_g * c_reg + i_g * tsg * g_g;
            hval  = o_g * tanhf(c_reg);
            h_lds[er][eh] = hval;
        }
        __syncthreads();
    }

    if (tid < 400) out[b0 * H_ + tid] = hval;
}

// ---------------------------------------------------------------------------
extern "C" void kernel_launch(void* const* d_in, const int* in_sizes, int n_in,
                              void* d_out, int out_size, void* d_ws, size_t ws_size,
                              hipStream_t stream) {
    const int*   traj     = (const int*)  d_in[0];
    // d_in[1] = lennew (unused by the reference)
    const int*   traj_len = (const int*)  d_in[2];
    const int*   tu       = (const int*)  d_in[3];
    const int*   tl       = (const int*)  d_in[4];
    const int*   tu_slot  = (const int*)  d_in[5];
    const int*   tl_slot  = (const int*)  d_in[6];
    const int*   su       = (const int*)  d_in[7];
    const int*   sl       = (const int*)  d_in[8];
    const int*   su_slot  = (const int*)  d_in[9];
    const int*   sl_slot  = (const int*)  d_in[10];
    const float* emb_loc  = (const float*)d_in[11];
    const float* emb_t    = (const float*)d_in[12];
    const float* emb_s    = (const float*)d_in[13];
    const float* W_ih     = (const float*)d_in[14];
    const float* W_hh     = (const float*)d_in[15];
    const float* b        = (const float*)d_in[16];
    const float* W_xt     = (const float*)d_in[17];
    const float* W_tt     = (const float*)d_in[18];
    const float* b_t      = (const float*)d_in[19];
    const float* W_xs     = (const float*)d_in[20];
    const float* W_ss     = (const float*)d_in[21];
    const float* b_s      = (const float*)d_in[22];

    float* P   = (float*)d_ws;              // 40001*600 = 24,000,600 floats (96.0 MB)
    float* P_t = P + (size_t)LOCN * NC;     // 9200 floats
    float* P_s = P_t + 92 * H_;             // 9200 floats

    proj_loc_kernel<<<(LOCN + PROWS - 1) / PROWS, 320, 0, stream>>>(
        emb_loc, W_ih, W_xt, W_xs, b, b_t, b_s, P);
    proj_ts_kernel<<<(2 * 92 * H_ + 255) / 256, 256, 0, stream>>>(
        emb_t, emb_s, W_tt, W_ss, P_t, P_s);
    lstm_rec_kernel<<<B_ / RB, NT, 0, stream>>>(
        traj, traj_len, tu, tl, tu_slot, tl_slot, su, sl, su_slot, sl_slot,
        P, P_t, P_s, W_hh, (float*)d_out);
}

// Round 7
// 774.016 us; speedup vs baseline: 2.2651x; 1.1452x over previous
//
#include <hip/hip_runtime.h>

#define B_    1024
#define T_    256
#define LOCN  40001
#define E_    100
#define H_    100
#define NC    600   // [0,400): gates (i|f|g|o) preact, [400,500): t preact, [500,600): s preact

// Fast sigmoid: rcp(1 + exp2(-x*log2e)). v_exp_f32 + v_rcp_f32 are ~1 ulp.
// ~4 VALU instrs vs ~25-30 for strict-IEEE expf+divide.
__device__ __forceinline__ float fsig(float x) {
    const float e = __builtin_amdgcn_exp2f(x * -1.442695040888963f);
    return __builtin_amdgcn_rcpf(1.f + e);
}

// ---------------------------------------------------------------------------
// Kernel 1: P_loc[LOC][600] = emb_loc @ [W_ih | W_xt | W_xs] + [b | b_t | b_s]
// (round-0 proven version, PROWS=16)
// ---------------------------------------------------------------------------
constexpr int PROWS = 16;
constexpr int PPAD  = 20;   // pad 16->20 dwords: keeps 16B alignment for b128, breaks pow2 bank stride

__global__ __launch_bounds__(320) void proj_loc_kernel(
    const float* __restrict__ emb_loc,
    const float* __restrict__ W_ih,   // [100][400]
    const float* __restrict__ W_xt,   // [100][100]
    const float* __restrict__ W_xs,   // [100][100]
    const float* __restrict__ b,      // [400]
    const float* __restrict__ b_t,    // [100]
    const float* __restrict__ b_s,    // [100]
    float* __restrict__ P)            // [LOC][600]
{
    __shared__ __attribute__((aligned(16))) float aT[E_][PPAD];  // transposed tile
    const int tid  = threadIdx.x;
    const int row0 = blockIdx.x * PROWS;

    for (int i = tid; i < PROWS * E_; i += 320) {
        int r = i / E_, k = i - r * E_;
        int rr = row0 + r;
        float v = 0.f;
        if (rr < LOCN) v = emb_loc[rr * E_ + k];
        aT[k][r] = v;
    }
    __syncthreads();
    if (tid >= 300) return;

    for (int cc = 0; cc < 2; ++cc) {
        const int c = tid + cc * 300;
        const float* wp; int stride; float bias;
        if (c < 400)      { wp = W_ih + c;         stride = 400; bias = b[c]; }
        else if (c < 500) { wp = W_xt + (c - 400); stride = 100; bias = b_t[c - 400]; }
        else              { wp = W_xs + (c - 500); stride = 100; bias = b_s[c - 500]; }

        float acc[PROWS];
        #pragma unroll
        for (int r = 0; r < PROWS; ++r) acc[r] = bias;

        for (int k = 0; k < E_; ++k) {
            float w = wp[(size_t)k * stride];
            #pragma unroll
            for (int r = 0; r < PROWS; ++r) acc[r] += aT[k][r] * w;
        }
        #pragma unroll
        for (int r = 0; r < PROWS; ++r) {
            int rr = row0 + r;
            if (rr < LOCN) P[(size_t)rr * NC + c] = acc[r];
        }
    }
}

// ---------------------------------------------------------------------------
// Kernel 2: P_t[92][100] = emb_t @ W_tt ; P_s[92][100] = emb_s @ W_ss
// ---------------------------------------------------------------------------
__global__ void proj_ts_kernel(
    const float* __restrict__ emb_t, const float* __restrict__ emb_s,
    const float* __restrict__ W_tt,  const float* __restrict__ W_ss,
    float* __restrict__ P_t, float* __restrict__ P_s)
{
    int idx = blockIdx.x * 256 + threadIdx.x;
    if (idx >= 2 * 92 * H_) return;
    int which = idx / (92 * H_);
    int rem   = idx - which * (92 * H_);
    int r = rem / H_, c = rem - r * H_;
    const float* e = which ? emb_s : emb_t;
    const float* W = which ? W_ss : W_tt;
    float acc = 0.f;
    #pragma unroll
    for (int k = 0; k < 12; ++k) acc += e[r * 12 + k] * W[k * H_ + c];
    (which ? P_s : P_t)[rem] = acc;
}

// ---------------------------------------------------------------------------
// Kernel 3: the recurrence. grid = 256 blocks, 4 batch rows/block, 704 thr.
// EXACT round-0 structure (685 us, still the best). Rounds 1-6 proved the
// kernel is VALU-instruction-count bound (dur x VALUBusy ~ 550 us across all
// partitionings). This round cuts the instruction count only:
//  - fsig(): hardware exp2+rcp sigmoid (4 instrs vs ~25-30 strict expf/div)
//  - epilogue tanh via exact identity 2*sig(2x)-1 (fast path)
//  - interp divide -> multiply by v_rcp
//  - readfirstlane(loc)/uniform off -> scalar-base addressing for gathers
//    (deletes per-lane 64-bit address mads; int loads become s_load)
// ---------------------------------------------------------------------------
constexpr int RB = 4;
constexpr int NT = 704;

__global__ __launch_bounds__(NT, 3) void lstm_rec_kernel(
    const int* __restrict__ traj,
    const int* __restrict__ traj_len_p,
    const int* __restrict__ tu,      const int* __restrict__ tl,
    const int* __restrict__ tu_slot, const int* __restrict__ tl_slot,
    const int* __restrict__ su,      const int* __restrict__ sl,
    const int* __restrict__ su_slot, const int* __restrict__ sl_slot,
    const float* __restrict__ P,     // [LOC][600]
    const float* __restrict__ P_t,   // [92][100]
    const float* __restrict__ P_s,   // [92][100]
    const float* __restrict__ W_hh,  // [100][400]
    float* __restrict__ out)         // [B][100]
{
    __shared__ __attribute__((aligned(16))) float h_lds[RB][H_];
    __shared__ float gates_lds[RB][400];
    __shared__ float tg_lds[RB][H_];
    __shared__ float sg_lds[RB][H_];
    __shared__ int   loc_lds[2][RB];

    const int tid = threadIdx.x;
    const int b0  = blockIdx.x * RB;
    int steps = traj_len_p[0] + 1;
    if (steps > T_) steps = T_;

    // W_hh column -> registers (persist across all 256 steps)
    float w[H_];
    if (tid < 400) {
        #pragma unroll
        for (int k = 0; k < H_; ++k) w[k] = W_hh[k * 400 + tid];
        ((float*)h_lds)[tid] = 0.f;
    }
    if (tid < RB) loc_lds[0][tid] = traj[(b0 + tid) * T_];

    const int er = tid / 100;        // epilogue row   (valid for tid<400)
    const int eh = tid - er * 100;   // epilogue h-idx
    float c_reg = 0.f, hval = 0.f;
    __syncthreads();

    for (int t = 0; t < steps; ++t) {
        const int buf = t & 1;

        if (tid >= 700) {                       // prefetch next step's locations
            int r = tid - 700;
            if (t + 1 < steps) loc_lds[buf ^ 1][r] = traj[(b0 + r) * T_ + t + 1];
        }

        if (tid < 400) {                        // ---- gates: gather + h @ W_hh ----
            const int n = tid;
            float gacc[RB];
            #pragma unroll
            for (int r = 0; r < RB; ++r) {
                const int loc = __builtin_amdgcn_readfirstlane(loc_lds[buf][r]);
                const float* __restrict__ Prow = P + (size_t)loc * NC;  // SGPR base
                gacc[r] = Prow[n];
            }

            float acc[RB] = {0.f, 0.f, 0.f, 0.f};
            #pragma unroll
            for (int k4 = 0; k4 < H_ / 4; ++k4) {
                #pragma unroll
                for (int r = 0; r < RB; ++r) {
                    float4 hv = *(const float4*)(&h_lds[r][k4 * 4]);
                    acc[r] += hv.x * w[k4 * 4 + 0];
                    acc[r] += hv.y * w[k4 * 4 + 1];
                    acc[r] += hv.z * w[k4 * 4 + 2];
                    acc[r] += hv.w * w[k4 * 4 + 3];
                }
            }
            const bool isg = (n >= 200 && n < 300);   // g-gate -> tanh via 2*sig(2x)-1
            #pragma unroll
            for (int r = 0; r < RB; ++r) {
                float v  = acc[r] + gacc[r];
                float xx = isg ? 2.f * v : v;
                float s  = fsig(xx);
                gates_lds[r][n] = isg ? (2.f * s - 1.f) : s;
            }
        }

        if (tid >= 448 && tid < 648) {          // ---- t/s gates (h-independent) ----
            const int  ch   = tid - 448;        // 0..199
            const bool is_t = ch < 100;
            const int  hx   = is_t ? ch : ch - 100;
            const int* up_a = is_t ? tu_slot : su_slot;
            const int* lo_a = is_t ? tl_slot : sl_slot;
            const int* ui_a = is_t ? tu : su;
            const int* li_a = is_t ? tl : sl;
            const float* Pq = is_t ? P_t : P_s;
            float* dst      = is_t ? &tg_lds[0][0] : &sg_lds[0][0];
            #pragma unroll
            for (int r = 0; r < RB; ++r) {
                const int off = __builtin_amdgcn_readfirstlane((b0 + r) * T_ + t);
                const int loc = __builtin_amdgcn_readfirstlane(loc_lds[buf][r]);
                const float* __restrict__ Prow = P + (size_t)loc * NC;  // SGPR base
                float gp  = Prow[400 + ch];
                float up  = (float)up_a[off];
                float low = (float)lo_a[off];
                int   ui  = ui_a[off], li = li_a[off];
                // interp @ W = (up*Pq[low_idx] + low*Pq[up_idx]) * rcp(max(up+low,1))
                const float inv = __builtin_amdgcn_rcpf(fmaxf(up + low, 1.f));
                float iv  = (up * Pq[li * H_ + hx] + low * Pq[ui * H_ + hx]) * inv;
                float pre = gp + iv;
                dst[r * H_ + hx] = fsig(pre);
            }
        }
        __syncthreads();

        if (tid < 400) {                        // ---- epilogue: c,h update ----
            float i_g = gates_lds[er][eh];
            float f_g = gates_lds[er][100 + eh];
            float g_g = gates_lds[er][200 + eh];
            float o_g = gates_lds[er][300 + eh];
            float tsg = tg_lds[er][eh] * sg_lds[er][eh];
            c_reg = f_g * c_reg + i_g * tsg * g_g;
            hval  = o_g * (2.f * fsig(2.f * c_reg) - 1.f);   // tanh = 2*sig(2x)-1
            h_lds[er][eh] = hval;
        }
        __syncthreads();
    }

    if (tid < 400) out[b0 * H_ + tid] = hval;
}

// ---------------------------------------------------------------------------
extern "C" void kernel_launch(void* const* d_in, const int* in_sizes, int n_in,
                              void* d_out, int out_size, void* d_ws, size_t ws_size,
                              hipStream_t stream) {
    const int*   traj     = (const int*)  d_in[0];
    // d_in[1] = lennew (unused by the reference)
    const int*   traj_len = (const int*)  d_in[2];
    const int*   tu       = (const int*)  d_in[3];
    const int*   tl       = (const int*)  d_in[4];
    const int*   tu_slot  = (const int*)  d_in[5];
    const int*   tl_slot  = (const int*)  d_in[6];
    const int*   su       = (const int*)  d_in[7];
    const int*   sl       = (const int*)  d_in[8];
    const int*   su_slot  = (const int*)  d_in[9];
    const int*   sl_slot  = (const int*)  d_in[10];
    const float* emb_loc  = (const float*)d_in[11];
    const float* emb_t    = (const float*)d_in[12];
    const float* emb_s    = (const float*)d_in[13];
    const float* W_ih     = (const float*)d_in[14];
    const float* W_hh     = (const float*)d_in[15];
    const float* b        = (const float*)d_in[16];
    const float* W_xt     = (const float*)d_in[17];
    const float* W_tt     = (const float*)d_in[18];
    const float* b_t      = (const float*)d_in[19];
    const float* W_xs     = (const float*)d_in[20];
    const float* W_ss     = (const float*)d_in[21];
    const float* b_s      = (const float*)d_in[22];

    float* P   = (float*)d_ws;              // 40001*600 = 24,000,600 floats (96.0 MB)
    float* P_t = P + (size_t)LOCN * NC;     // 9200 floats
    float* P_s = P_t + 92 * H_;             // 9200 floats

    proj_loc_kernel<<<(LOCN + PROWS - 1) / PROWS, 320, 0, stream>>>(
        emb_loc, W_ih, W_xt, W_xs, b, b_t, b_s, P);
    proj_ts_kernel<<<(2 * 92 * H_ + 255) / 256, 256, 0, stream>>>(
        emb_t, emb_s, W_tt, W_ss, P_t, P_s);
    lstm_rec_kernel<<<B_ / RB, NT, 0, stream>>>(
        traj, traj_len, tu, tl, tu_slot, tl_slot, su, sl, su_slot, sl_slot,
        P, P_t, P_s, W_hh, (float*)d_out);
}